// Round 12
// baseline (273.555 us; speedup 1.0000x reference)
//
#include <hip/hip_runtime.h>
#include <math.h>

// Problem constants (Attention_9242769621638)
#define NB     4      // batch
#define SEQ    2048   // sequence length
#define DMODEL 1024   // model dim
#define NH     16     // heads
#define DHEAD  64     // dim per head
#define QKVC   3072   // 3 * NH * DHEAD
// SCALE = DMODEL^-0.5 = 1/32; folded with log2(e) into Q so softmax = exp2(S).
// Scores S_true = q.k/32 have std ~0.25, |S|<~1.7 -> fixed-max softmax safe.
#define QSCALE_LOG2E 0.04508422f  // (1/32) * log2(e)

typedef __attribute__((ext_vector_type(8))) short bf16x8;  // 8 bf16 in 4 VGPRs
typedef __attribute__((ext_vector_type(4))) float f32x4;
typedef __attribute__((ext_vector_type(16))) float f32x16;

// fp32 -> bf16 round-to-nearest-even
static __device__ __forceinline__ short f2bf(float f) {
  union { float f; unsigned u; } v; v.f = f;
  unsigned r = v.u + 0x7fff + ((v.u >> 16) & 1);
  return (short)(r >> 16);
}

// raw HW packed cvt: low16 = bf16(a), high16 = bf16(b), RNE. 1 VALU op.
static __device__ __forceinline__ unsigned cvtpk_bf16(float a, float b) {
  unsigned d;
  asm("v_cvt_pk_bf16_f32 %0, %1, %2" : "=v"(d) : "v"(a), "v"(b));
  return d;
}

// 2^x without the libm denormal-range guard. MUST be the compiler intrinsic,
// not inline asm: v_exp_f32 is a TRANS op with a mandatory wait-state before
// a dependent VALU read; the hazard recognizer can't see inside asm blocks
// (round-6 failure: inline-asm exp2 -> intermittent stale reads, absmax 2e-2).
static __device__ __forceinline__ float exp2_hw(float x) {
#if __has_builtin(__builtin_amdgcn_exp2f)
  return __builtin_amdgcn_exp2f(x);
#else
  return __builtin_exp2f(x);
#endif
}

// v_permlane32_swap_b32 a, b: exchanges lanes 32..63 of a with lanes 0..31 of b.
static __device__ __forceinline__ void plswap(unsigned &a, unsigned &b) {
  asm("v_permlane32_swap_b32 %0, %1" : "+v"(a), "+v"(b));
}

// async global->LDS, 16 B per lane. LDS dest = wave-uniform base + lane*16.
static __device__ __forceinline__ void gl2lds16(const void* g, void* l) {
  __builtin_amdgcn_global_load_lds(
      (const __attribute__((address_space(1))) unsigned int*)g,
      (__attribute__((address_space(3))) unsigned int*)l, 16, 0, 0);
}

// ---------------------------------------------------------------------------
// Fused preprocessing (one launch instead of three):
//   blocks [0, 4096)      : x fp32 -> xb bf16 (8 elems/thread)
//   blocks [4096, 4864)   : w_qkv [1024][3072] -> wqbt [3072][1024] bf16
//   blocks [4864, 5120)   : w_out [1024][1024] -> wobt [1024][1024]^T bf16
// ---------------------------------------------------------------------------
static __device__ __forceinline__ void convt_body(
    const float* __restrict__ in, short* __restrict__ out, int R, int C,
    int bx, int by) {
  __shared__ float T[64][65];
  const int r0 = by * 64, c0 = bx * 64;
  const int t = threadIdx.x;
  const int lr = t >> 2, lc = (t & 3) * 16;
  const float* ip = in + (size_t)(r0 + lr) * C + c0 + lc;
#pragma unroll
  for (int i = 0; i < 4; ++i) {
    float4 v = *(const float4*)(ip + i * 4);
    T[lr][lc + i * 4 + 0] = v.x; T[lr][lc + i * 4 + 1] = v.y;
    T[lr][lc + i * 4 + 2] = v.z; T[lr][lc + i * 4 + 3] = v.w;
  }
  __syncthreads();
  short* op = out + (size_t)(c0 + lr) * R + r0 + lc;
#pragma unroll
  for (int i = 0; i < 4; ++i) {
    short4 s;
    s.x = f2bf(T[lc + i * 4 + 0][lr]); s.y = f2bf(T[lc + i * 4 + 1][lr]);
    s.z = f2bf(T[lc + i * 4 + 2][lr]); s.w = f2bf(T[lc + i * 4 + 3][lr]);
    *(short4*)(op + i * 4) = s;
  }
}

__global__ __launch_bounds__(256) void fused_pre(
    const float* __restrict__ x, short* __restrict__ xb,
    const float* __restrict__ w_qkv, short* __restrict__ wqbt,
    const float* __restrict__ w_out, short* __restrict__ wobt) {
  const int bid = blockIdx.x;
  if (bid < 4096) {
    int i = (bid * 256 + threadIdx.x) * 8;
    float4 a = *(const float4*)(x + i);
    float4 b = *(const float4*)(x + i + 4);
    bf16x8 s;
    s[0] = f2bf(a.x); s[1] = f2bf(a.y); s[2] = f2bf(a.z); s[3] = f2bf(a.w);
    s[4] = f2bf(b.x); s[5] = f2bf(b.y); s[6] = f2bf(b.z); s[7] = f2bf(b.w);
    *(bf16x8*)(xb + i) = s;
  } else if (bid < 4096 + 768) {
    const int idx = bid - 4096;                 // 48 tiles per row
    convt_body(w_qkv, wqbt, DMODEL, QKVC, idx % 48, idx / 48);
  } else {
    const int idx = bid - 4864;                 // 16 tiles per row
    convt_body(w_out, wobt, DMODEL, DMODEL, idx % 16, idx / 16);
  }
}

// ---------------------------------------------------------------------------
// NEW: 256x256 2-phase dbuf GEMM (guide m230-V0 recipe, 655-682 TF @ K~1024).
// Why round-9's 256x128 failed but this should not: per K-step a 256^2 block
// runs 512 MFMA (~614 cyc/SIMD at 2 waves/SIMD) against 64 KB staged
// (128 FLOP/B) -- enough compute shadow to hide the prefetch latency that
// 256x128 (307 cyc, 87 FLOP/B) and 128^2 (64 FLOP/B) expose at the barrier.
// Same proven-correct loop family as round 9 (passed refcheck), same
// chunk-XOR swizzle; 8 waves as 2x4 grid of 128x64 outputs; acc 128 VGPR +
// per-mt transient aA keeps peak ~160 under the (512,2) 256-reg budget.
// One barrier per K-step; STAGE(next) issued before compute on cur.
// Used for GEMM1 only (N=3072 -> 384 blocks). GEMM2 (N=1024) stays on the
// 128^2 kernel: a 256^2 grid there is 128 blocks = half the chip idle.
// Requires M%256==0, N%256==0, K%64==0.
// ---------------------------------------------------------------------------
__global__ __launch_bounds__(512, 2) void gemm_bf16_256sq(
    const short* __restrict__ A, const short* __restrict__ Bt,
    const float* __restrict__ bias, void* __restrict__ C,
    int M, int N, int K, int c_bf16, float q_scale, int q_cols) {
  __shared__ short As[2][256 * 64];  // [buf][m][k], 128B rows, chunk-XOR
  __shared__ short Bs[2][256 * 64];  // [buf][n][k]
  const int t = threadIdx.x;
  const int w = t >> 6, lane = t & 63, quad = lane >> 4, l16 = lane & 15;
  const int wr = (w >> 2) * 128, wc = (w & 3) * 64;  // 2x4 wave grid
  const int bn = blockIdx.x * 256, bm = blockIdx.y * 256;
  const int r7 = l16 & 7;  // row&7 for all frag rows (wr/wc, *16 are %8==0)

  f32x4 acc[8][4];
#pragma unroll
  for (int i = 0; i < 8; ++i)
#pragma unroll
    for (int j = 0; j < 4; ++j) acc[i][j] = (f32x4){0.f, 0.f, 0.f, 0.f};

  // Stage one 64-K tile (A: 32 KB, B: 32 KB) into buffer buf.
  // Dest o = i*8192 + t*16; row = o>>7; phys chunk (o>>4)&7 holds source
  // chunk ((o>>4)&7)^(row&7) (pre-swizzled source, rule #21).
  auto STAGE = [&](int k0, int buf) {
#pragma unroll
    for (int i = 0; i < 4; ++i) {
      int o = i * 8192 + t * 16;
      int row = o >> 7;
      int sc = (((o >> 4) & 7) ^ (row & 7)) * 16;
      gl2lds16((const char*)A + ((size_t)(bm + row) * K + k0) * 2 + sc,
               (char*)&As[buf][0] + (o - lane * 16));
      gl2lds16((const char*)Bt + ((size_t)(bn + row) * K + k0) * 2 + sc,
               (char*)&Bs[buf][0] + (o - lane * 16));
    }
  };

  STAGE(0, 0);
  __syncthreads();  // drain: buf 0 resident

  int cur = 0;
  for (int k0 = 0; k0 < K; k0 += 64) {
    const bool nxt = (k0 + 64) < K;
    if (nxt) STAGE(k0 + 64, cur ^ 1);  // issue loads; land under 512 MFMA

    const short* AsC = As[cur];
    const short* BsC = Bs[cur];
#pragma unroll
    for (int kc = 0; kc < 2; ++kc) {
      const int cx = ((kc * 4 + quad) ^ r7) * 8;  // swizzled k-chunk (shorts)
      bf16x8 bB[4];
#pragma unroll
      for (int nt = 0; nt < 4; ++nt)
        bB[nt] = *(const bf16x8*)&BsC[(wc + nt * 16 + l16) * 64 + cx];
      __builtin_amdgcn_s_setprio(1);
#pragma unroll
      for (int mt = 0; mt < 8; ++mt) {
        bf16x8 aA = *(const bf16x8*)&AsC[(wr + mt * 16 + l16) * 64 + cx];
#pragma unroll
        for (int nt = 0; nt < 4; ++nt)
          acc[mt][nt] = __builtin_amdgcn_mfma_f32_16x16x32_bf16(
              aA, bB[nt], acc[mt][nt], 0, 0, 0);
      }
      __builtin_amdgcn_s_setprio(0);
    }

    if (nxt) {
      __syncthreads();  // reads of cur done + staged cur^1 drained
      cur ^= 1;
    }
  }

  const int row0 = bm + wr + quad * 4;
  const int col0 = bn + wc + l16;
  if (c_bf16) {
    const float sc = (bn < q_cols) ? q_scale : 1.0f;  // 1024 % 256 == 0
    short* Cb = (short*)C;
#pragma unroll
    for (int mt = 0; mt < 8; ++mt)
#pragma unroll
      for (int nt = 0; nt < 4; ++nt)
#pragma unroll
        for (int r = 0; r < 4; ++r)
          Cb[(size_t)(row0 + mt * 16 + r) * N + col0 + nt * 16] =
              f2bf(acc[mt][nt][r] * sc);
  } else {
    float* Cf = (float*)C;
    float bv[4];
#pragma unroll
    for (int nt = 0; nt < 4; ++nt) bv[nt] = bias ? bias[col0 + nt * 16] : 0.f;
#pragma unroll
    for (int mt = 0; mt < 8; ++mt)
#pragma unroll
      for (int nt = 0; nt < 4; ++nt)
#pragma unroll
        for (int r = 0; r < 4; ++r)
          Cf[(size_t)(row0 + mt * 16 + r) * N + col0 + nt * 16] =
              acc[mt][nt][r] + bv[nt];
  }
}

// ---------------------------------------------------------------------------
// bf16 MFMA GEMM (128x128): round-8/10 proven config. Used for GEMM2 only
// (N=1024 -> 256 blocks = full chip; 128^2 wins there by occupancy).
// Requires (N/128)%8==0, K%64==0.
// ---------------------------------------------------------------------------
__global__ __launch_bounds__(256, 4) void gemm_bf16_128(
    const short* __restrict__ A, const short* __restrict__ Bt,
    const float* __restrict__ bias, void* __restrict__ C,
    int M, int N, int K, int c_bf16, float q_scale, int q_cols) {
  __shared__ short As[128 * 64];  // [m][k], 128B rows, chunk-XOR content
  __shared__ short Bs[128 * 64];  // [n][k]
  const int t = threadIdx.x;
  const int w = t >> 6, lane = t & 63, quad = lane >> 4, l16 = lane & 15;
  const int wm = (w >> 1) * 64, wn = (w & 1) * 64;
  // XCD-ownership mapping (bijective: bid < 8*cpx*(M/128), nbn = 8*cpx)
  const int nbn = N >> 7, cpx = nbn >> 3;
  const int xcd = blockIdx.x & 7, ii = blockIdx.x >> 3;
  const int bn = (xcd * cpx + ii % cpx) * 128;
  const int bm = (ii / cpx) * 128;
  const int r7 = l16 & 7;  // row&7 for all frag rows (wm/wn, mt*16 are %8==0)

  f32x4 acc[4][4];
#pragma unroll
  for (int i = 0; i < 4; ++i)
#pragma unroll
    for (int j = 0; j < 4; ++j) acc[i][j] = (f32x4){0.f, 0.f, 0.f, 0.f};

  for (int k0 = 0; k0 < K; k0 += 64) {
    __syncthreads();
#pragma unroll
    for (int i = 0; i < 4; ++i) {
      int o = w * 4096 + i * 1024 + lane * 16;       // dest byte offset
      int row = o >> 7;
      int sc = (((o >> 4) & 7) ^ (row & 7)) * 16;    // swizzled source k-bytes
      gl2lds16((const char*)A + ((size_t)(bm + row) * K + k0) * 2 + sc,
               (char*)As + (o - lane * 16));
      gl2lds16((const char*)Bt + ((size_t)(bn + row) * K + k0) * 2 + sc,
               (char*)Bs + (o - lane * 16));
    }
    __syncthreads();

#pragma unroll
    for (int kc = 0; kc < 2; ++kc) {
      bf16x8 aA[4], bB[4];
#pragma unroll
      for (int mt = 0; mt < 4; ++mt)
        aA[mt] = *(const bf16x8*)&As[(wm + mt * 16 + l16) * 64 +
                                     (((kc * 4 + quad) ^ r7) * 8)];
#pragma unroll
      for (int nt = 0; nt < 4; ++nt)
        bB[nt] = *(const bf16x8*)&Bs[(wn + nt * 16 + l16) * 64 +
                                     (((kc * 4 + quad) ^ r7) * 8)];
#pragma unroll
      for (int mt = 0; mt < 4; ++mt)
#pragma unroll
        for (int nt = 0; nt < 4; ++nt)
          acc[mt][nt] = __builtin_amdgcn_mfma_f32_16x16x32_bf16(
              aA[mt], bB[nt], acc[mt][nt], 0, 0, 0);
    }
  }

  const int row0 = bm + wm + quad * 4;
  const int col0 = bn + wn + l16;
  if (c_bf16) {
    const float sc = (bn < q_cols) ? q_scale : 1.0f;
    short* Cb = (short*)C;
#pragma unroll
    for (int mt = 0; mt < 4; ++mt)
#pragma unroll
      for (int nt = 0; nt < 4; ++nt)
#pragma unroll
        for (int r = 0; r < 4; ++r)
          Cb[(size_t)(row0 + mt * 16 + r) * N + col0 + nt * 16] =
              f2bf(acc[mt][nt][r] * sc);
  } else {
    float* Cf = (float*)C;
    float bv[4];
#pragma unroll
    for (int nt = 0; nt < 4; ++nt) bv[nt] = bias ? bias[col0 + nt * 16] : 0.f;
#pragma unroll
    for (int mt = 0; mt < 4; ++mt)
#pragma unroll
      for (int nt = 0; nt < 4; ++nt)
#pragma unroll
        for (int r = 0; r < 4; ++r)
          Cf[(size_t)(row0 + mt * 16 + r) * N + col0 + nt * 16] =
              acc[mt][nt][r] + bv[nt];
  }
}

// ---------------------------------------------------------------------------
// bf16-MFMA flash attention, swapped-QK^T 32x32, 8-wave / 256-Q-row blocks.
// FROZEN at the round-8/10 proven state (~92 us, VGPR 64, no spill):
// exp2 via builtin, WRITEV between jt=0/jt=1, tree rowsum, setprio.
// ---------------------------------------------------------------------------
#define LSTR 72  // Vt row stride in bf16 (144 B): skewed banks + b128 aligned

typedef union { unsigned u[4]; bf16x8 v; } U8;

__global__ __launch_bounds__(512, 4) void attn_flash_mfma32(
    const short* __restrict__ qkv, short* __restrict__ attn_out) {
  __shared__ short Kt[2][64 * 64];    // linear; content XOR-swizzled
  __shared__ short Vt[2][64 * LSTR];  // Vt[d][j] (transposed), skewed
  // XCD-chunked bijective swizzle: 8 consecutive logical blocks (the 8
  // q-blocks sharing one (b,h) K/V stream) land on ONE XCD's L2.
  const int wg = (blockIdx.x & 7) * 64 + (blockIdx.x >> 3);
  const int qb = wg & 7, h = (wg >> 3) & 15, b = wg >> 7;
  const int q0 = qb * 256;
  const int t    = threadIdx.x;
  const int w    = t >> 6;
  const int lane = t & 63;
  const int l32  = lane & 31;
  const int hi   = lane >> 5;

  const short* base = qkv + (size_t)b * SEQ * QKVC;

  // Q B-fragments (loop-invariant): col=q=l32, k=d = dc*16 + hi*8 + e
  bf16x8 bQ[4];
  {
    const short* qp = base + (size_t)(q0 + w * 32 + l32) * QKVC + h * DHEAD + hi * 8;
#pragma unroll
    for (int dc = 0; dc < 4; ++dc) bQ[dc] = *(const bf16x8*)(qp + dc * 16);
  }

  // K staging: 512 lanes x 16B = whole 64x64 tile in one gl2lds per thread.
  // Lane covers dest row kj = w*8 + (lane>>3), chunk c = lane&7; source
  // chunk = c ^ (kj&7)  (inverse XOR applied at source; read applies same).
  const int kj = w * 8 + (lane >> 3);
  const int kc = (lane & 7) ^ (kj & 7);
  const short* ksrc = base + (size_t)kj * QKVC + DMODEL + h * DHEAD + kc * 8;

  // V staging: thread t -> j-pair rows {2p,2p+1}, d cols q4..q4+3.
  const int pv = t & 31, q4 = (t >> 5) * 4;
  const short* vsrc = base + (size_t)(2 * pv) * QKVC + 2 * DMODEL + h * DHEAD + q4;
  ushort4 va, vb;  // V prefetch regs (rows 2p, 2p+1)

  auto LOADK = [&](int j0, int buf) {
    gl2lds16(ksrc + (size_t)j0 * QKVC, (char*)&Kt[buf][0] + w * 1024);
  };
  auto LOADV = [&](int j0) {
    const short* vp = vsrc + (size_t)j0 * QKVC;
    va = *(const ushort4*)vp;
    vb = *(const ushort4*)(vp + QKVC);
  };
  auto WRITEV = [&](int buf) {
    unsigned* vd = (unsigned*)&Vt[buf][q4 * LSTR + 2 * pv];
    vd[0]   = (unsigned)va.x | ((unsigned)vb.x << 16);
    vd[36]  = (unsigned)va.y | ((unsigned)vb.y << 16);  // +LSTR shorts = 36 dw
    vd[72]  = (unsigned)va.z | ((unsigned)vb.z << 16);
    vd[108] = (unsigned)va.w | ((unsigned)vb.w << 16);
  };

  f32x16 O0, O1;
#pragma unroll
  for (int i = 0; i < 16; ++i) { O0[i] = 0.f; O1[i] = 0.f; }
  float rs = 0.f;

  LOADK(0, 0);
  LOADV(0);
  WRITEV(0);
  __syncthreads();  // vmcnt(0)+lgkmcnt(0) drain: K in LDS, V written

  int cur = 0;
  for (int j0 = 0; j0 < SEQ; j0 += 64) {
    const bool nxt = (j0 + 64) < SEQ;
    if (nxt) {                      // issue next tile's loads; latency hides
      LOADK(j0 + 64, cur ^ 1);      // buf cur^1 fully consumed at last barrier
      LOADV(j0 + 64);
    }

    const short* KtC = Kt[cur];
    const short* VtC = Vt[cur];
    const int r7 = l32 & 7;
#pragma unroll
    for (int jt = 0; jt < 2; ++jt) {
      // S^T = K (rows j) x Q^T: A row = j = jt*32 + l32, k = d
      f32x16 accS;
#pragma unroll
      for (int i = 0; i < 16; ++i) accS[i] = 0.f;
      const short* ktb = KtC + (jt * 32 + l32) * 64;
      __builtin_amdgcn_s_setprio(1);
#pragma unroll
      for (int dc = 0; dc < 4; ++dc) {
        bf16x8 aK = *(const bf16x8*)(ktb + (((dc << 1) | hi) ^ r7) * 8);
        accS = __builtin_amdgcn_mfma_f32_32x32x16_bf16(aK, bQ[dc], accS, 0, 0, 0);
      }
      __builtin_amdgcn_s_setprio(0);
      // lane holds S[q=l32][j = jt*32 + (r&3)+8*(r>>2)+4*hi], r=0..15
      float p[16];
#pragma unroll
      for (int r = 0; r < 16; ++r) p[r] = exp2_hw(accS[r]);
      {  // tree rowsum: transient temps only, dep chain 16 -> 5
        float t0 = (p[0] + p[1]) + (p[2] + p[3]);
        float t1 = (p[4] + p[5]) + (p[6] + p[7]);
        float t2 = (p[8] + p[9]) + (p[10] + p[11]);
        float t3 = (p[12] + p[13]) + (p[14] + p[15]);
        rs += (t0 + t1) + (t2 + t3);
      }
      // pack pairs (j,j+1) then swap hi<->lo halves -> contiguous k=8 frags
      unsigned ua = cvtpk_bf16(p[0], p[1]),   ub = cvtpk_bf16(p[2], p[3]);
      unsigned uc = cvtpk_bf16(p[4], p[5]),   ud = cvtpk_bf16(p[6], p[7]);
      unsigned ue = cvtpk_bf16(p[8], p[9]),   uf = cvtpk_bf16(p[10], p[11]);
      unsigned ug = cvtpk_bf16(p[12], p[13]), uh = cvtpk_bf16(p[14], p[15]);
      plswap(ua, uc); plswap(ub, ud);  // frag jc=jt*2:   words {ua,ub,uc,ud}
      plswap(ue, ug); plswap(uf, uh);  // frag jc=jt*2+1: words {ue,uf,ug,uh}
      U8 fa, fb;
      fa.u[0] = ua; fa.u[1] = ub; fa.u[2] = uc; fa.u[3] = ud;
      fb.u[0] = ue; fb.u[1] = uf; fb.u[2] = ug; fb.u[3] = uh;
      // PV: O[q][d] += P[q][j] V[j][d]; B col = d = dt*32 + l32, k = j
      __builtin_amdgcn_s_setprio(1);
#pragma unroll
      for (int dt = 0; dt < 2; ++dt) {
        const short* vt = VtC + (dt * 32 + l32) * LSTR + hi * 8;
        bf16x8 bV0 = *(const bf16x8*)(vt + (jt * 2) * 16);
        bf16x8 bV1 = *(const bf16x8*)(vt + (jt * 2 + 1) * 16);
        f32x16& Od = dt ? O1 : O0;
        Od = __builtin_amdgcn_mfma_f32_32x32x16_bf16(fa.v, bV0, Od, 0, 0, 0);
        Od = __builtin_amdgcn_mfma_f32_32x32x16_bf16(fb.v, bV1, Od, 0, 0, 0);
      }
      __builtin_amdgcn_s_setprio(0);
      // After jt=0: write next tile's V (buf cur^1, disjoint from all reads
      // of cur this epoch). V global loads have had a half-tile of compute
      // to land; ds_writes overlap jt=1 instead of stalling pre-barrier.
      if (jt == 0 && nxt) WRITEV(cur ^ 1);
    }

    if (nxt) {
      __syncthreads();   // single barrier per KV tile (drains gl2lds too)
      cur ^= 1;
    }
  }

  // rs: lane l holds partial row-sum for q=l32 (hi halves cover disjoint j)
  rs += __shfl_xor(rs, 32, 64);
  const float inv_own = 1.f / rs;
  short* op0 = attn_out + ((size_t)b * SEQ + q0 + w * 32) * DMODEL + h * DHEAD + l32;
#pragma unroll
  for (int r = 0; r < 16; ++r) {
    const int q = (r & 3) + 8 * (r >> 2) + 4 * hi;  // O row for this reg
    const float inv = __shfl(inv_own, q, 64);       // lane q holds 1/rowsum(q)
    short* op = op0 + (size_t)q * DMODEL;
    op[0]  = f2bf(O0[r] * inv);
    op[32] = f2bf(O1[r] * inv);
  }
}

// ---------------------------------------------------------------------------
// Launch: fused convert -> bf16 GEMM (qkv, Q pre-scaled) -> attn -> GEMM+bias
// Workspace (bf16): xb 16MB | wqbt 6MB | wobt 2MB | qkvb 48MB | attnb 16MB
// ---------------------------------------------------------------------------
extern "C" void kernel_launch(void* const* d_in, const int* in_sizes, int n_in,
                              void* d_out, int out_size, void* d_ws, size_t ws_size,
                              hipStream_t stream) {
  const float* x     = (const float*)d_in[0];
  const float* w_qkv = (const float*)d_in[1];
  const float* w_out = (const float*)d_in[2];
  const float* b_out = (const float*)d_in[3];
  float* out = (float*)d_out;

  short* xb    = (short*)d_ws;                       // 8192*1024
  short* wqbt  = xb   + (size_t)8192 * 1024;         // 3072*1024 (w_qkv^T)
  short* wobt  = wqbt + (size_t)3072 * 1024;         // 1024*1024 (w_out^T)
  short* qkvb  = wobt + (size_t)1024 * 1024;         // 8192*3072
  short* attnb = qkvb + (size_t)8192 * 3072;         // 8192*1024

  fused_pre<<<dim3(4096 + 768 + 256), 256, 0, stream>>>(
      x, xb, w_qkv, wqbt, w_out, wobt);

  // GEMM1: 256x256 2-phase dbuf, grid (3072/256, 8192/256) = (12, 32)
  gemm_bf16_256sq<<<dim3(QKVC / 256, (NB * SEQ) / 256), 512, 0, stream>>>(
      xb, wqbt, nullptr, qkvb, NB * SEQ, QKVC, DMODEL, 1, QSCALE_LOG2E, DMODEL);

  attn_flash_mfma32<<<dim3(512), 512, 0, stream>>>(qkvb, attnb);

  // GEMM2: 128x128 (N=1024 -> 256 blocks = full chip)
  gemm_bf16_128<<<dim3((DMODEL / 128) * ((NB * SEQ) / 128)), 256, 0, stream>>>(
      attnb, wobt, b_out, out, NB * SEQ, DMODEL, DMODEL, 0, 1.0f, 0);
}

// Round 13
// 259.284 us; speedup vs baseline: 1.0550x; 1.0550x over previous
//
#include <hip/hip_runtime.h>
#include <math.h>

// Problem constants (Attention_9242769621638)
#define NB     4      // batch
#define SEQ    2048   // sequence length
#define DMODEL 1024   // model dim
#define NH     16     // heads
#define DHEAD  64     // dim per head
#define QKVC   3072   // 3 * NH * DHEAD
// SCALE = DMODEL^-0.5 = 1/32; folded with log2(e) into Q so softmax = exp2(S).
// Scores S_true = q.k/32 have std ~0.25, |S|<~1.7 -> fixed-max softmax safe.
#define QSCALE_LOG2E 0.04508422f  // (1/32) * log2(e)

typedef __attribute__((ext_vector_type(8))) short bf16x8;  // 8 bf16 in 4 VGPRs
typedef __attribute__((ext_vector_type(4))) float f32x4;
typedef __attribute__((ext_vector_type(16))) float f32x16;

// fp32 -> bf16 round-to-nearest-even
static __device__ __forceinline__ short f2bf(float f) {
  union { float f; unsigned u; } v; v.f = f;
  unsigned r = v.u + 0x7fff + ((v.u >> 16) & 1);
  return (short)(r >> 16);
}

// raw HW packed cvt: low16 = bf16(a), high16 = bf16(b), RNE. 1 VALU op.
static __device__ __forceinline__ unsigned cvtpk_bf16(float a, float b) {
  unsigned d;
  asm("v_cvt_pk_bf16_f32 %0, %1, %2" : "=v"(d) : "v"(a), "v"(b));
  return d;
}

// 2^x without the libm denormal-range guard. MUST be the compiler intrinsic,
// not inline asm: v_exp_f32 is a TRANS op with a mandatory wait-state before
// a dependent VALU read; the hazard recognizer can't see inside asm blocks
// (round-6 failure: inline-asm exp2 -> intermittent stale reads, absmax 2e-2).
static __device__ __forceinline__ float exp2_hw(float x) {
#if __has_builtin(__builtin_amdgcn_exp2f)
  return __builtin_amdgcn_exp2f(x);
#else
  return __builtin_exp2f(x);
#endif
}

// v_permlane32_swap_b32 a, b: exchanges lanes 32..63 of a with lanes 0..31 of b.
static __device__ __forceinline__ void plswap(unsigned &a, unsigned &b) {
  asm("v_permlane32_swap_b32 %0, %1" : "+v"(a), "+v"(b));
}

// async global->LDS, 16 B per lane. LDS dest = wave-uniform base + lane*16.
static __device__ __forceinline__ void gl2lds16(const void* g, void* l) {
  __builtin_amdgcn_global_load_lds(
      (const __attribute__((address_space(1))) unsigned int*)g,
      (__attribute__((address_space(3))) unsigned int*)l, 16, 0, 0);
}

// ---------------------------------------------------------------------------
// Fused preprocessing (one launch instead of three):
//   blocks [0, 4096)      : x fp32 -> xb bf16 (8 elems/thread)
//   blocks [4096, 4864)   : w_qkv [1024][3072] -> wqbt [3072][1024] bf16
//   blocks [4864, 5120)   : w_out [1024][1024] -> wobt [1024][1024]^T bf16
// ---------------------------------------------------------------------------
static __device__ __forceinline__ void convt_body(
    const float* __restrict__ in, short* __restrict__ out, int R, int C,
    int bx, int by) {
  __shared__ float T[64][65];
  const int r0 = by * 64, c0 = bx * 64;
  const int t = threadIdx.x;
  const int lr = t >> 2, lc = (t & 3) * 16;
  const float* ip = in + (size_t)(r0 + lr) * C + c0 + lc;
#pragma unroll
  for (int i = 0; i < 4; ++i) {
    float4 v = *(const float4*)(ip + i * 4);
    T[lr][lc + i * 4 + 0] = v.x; T[lr][lc + i * 4 + 1] = v.y;
    T[lr][lc + i * 4 + 2] = v.z; T[lr][lc + i * 4 + 3] = v.w;
  }
  __syncthreads();
  short* op = out + (size_t)(c0 + lr) * R + r0 + lc;
#pragma unroll
  for (int i = 0; i < 4; ++i) {
    short4 s;
    s.x = f2bf(T[lc + i * 4 + 0][lr]); s.y = f2bf(T[lc + i * 4 + 1][lr]);
    s.z = f2bf(T[lc + i * 4 + 2][lr]); s.w = f2bf(T[lc + i * 4 + 3][lr]);
    *(short4*)(op + i * 4) = s;
  }
}

__global__ __launch_bounds__(256) void fused_pre(
    const float* __restrict__ x, short* __restrict__ xb,
    const float* __restrict__ w_qkv, short* __restrict__ wqbt,
    const float* __restrict__ w_out, short* __restrict__ wobt) {
  const int bid = blockIdx.x;
  if (bid < 4096) {
    int i = (bid * 256 + threadIdx.x) * 8;
    float4 a = *(const float4*)(x + i);
    float4 b = *(const float4*)(x + i + 4);
    bf16x8 s;
    s[0] = f2bf(a.x); s[1] = f2bf(a.y); s[2] = f2bf(a.z); s[3] = f2bf(a.w);
    s[4] = f2bf(b.x); s[5] = f2bf(b.y); s[6] = f2bf(b.z); s[7] = f2bf(b.w);
    *(bf16x8*)(xb + i) = s;
  } else if (bid < 4096 + 768) {
    const int idx = bid - 4096;                 // 48 tiles per row
    convt_body(w_qkv, wqbt, DMODEL, QKVC, idx % 48, idx / 48);
  } else {
    const int idx = bid - 4864;                 // 16 tiles per row
    convt_body(w_out, wobt, DMODEL, DMODEL, idx % 16, idx / 16);
  }
}

// ---------------------------------------------------------------------------
// bf16 MFMA GEMM: C[M,N] = A[M,K] @ Bt[N,K]^T (+bias). Round-10/11 proven
// best config: m97 128x128 structure, BK=64, chunk-XOR LDS swizzle via
// pre-swizzled gl2lds source (rule #21), XCD-ownership block mapping,
// (256,4) launch bounds (proven neutral, kept).
// Session ledger (all vs this config): BK=64/swizzle/XCD-map +3us;
// 256x128 dbuf -8us (r9); 256^2 dbuf -12us (r12); launch-bounds 0 (r11).
// The multi-block-per-CU 2-barrier structure is the measured optimum of the
// reachable family at K=1024; the next jump requires the full 8-phase
// co-designed template (counted vmcnt + phase interleave), deferred.
// Requires (N/128)%8==0, K%64==0 (call sites: N=3072/1024, K=1024).
// ---------------------------------------------------------------------------
__global__ __launch_bounds__(256, 4) void gemm_bf16_128(
    const short* __restrict__ A, const short* __restrict__ Bt,
    const float* __restrict__ bias, void* __restrict__ C,
    int M, int N, int K, int c_bf16, float q_scale, int q_cols) {
  __shared__ short As[128 * 64];  // [m][k], 128B rows, chunk-XOR content
  __shared__ short Bs[128 * 64];  // [n][k]
  const int t = threadIdx.x;
  const int w = t >> 6, lane = t & 63, quad = lane >> 4, l16 = lane & 15;
  const int wm = (w >> 1) * 64, wn = (w & 1) * 64;
  // XCD-ownership mapping (bijective: bid < 8*cpx*(M/128), nbn = 8*cpx)
  const int nbn = N >> 7, cpx = nbn >> 3;
  const int xcd = blockIdx.x & 7, ii = blockIdx.x >> 3;
  const int bn = (xcd * cpx + ii % cpx) * 128;
  const int bm = (ii / cpx) * 128;
  const int r7 = l16 & 7;  // row&7 for all frag rows (wm/wn, mt*16 are %8==0)

  f32x4 acc[4][4];
#pragma unroll
  for (int i = 0; i < 4; ++i)
#pragma unroll
    for (int j = 0; j < 4; ++j) acc[i][j] = (f32x4){0.f, 0.f, 0.f, 0.f};

  for (int k0 = 0; k0 < K; k0 += 64) {
    __syncthreads();
#pragma unroll
    for (int i = 0; i < 4; ++i) {
      int o = w * 4096 + i * 1024 + lane * 16;       // dest byte offset
      int row = o >> 7;
      int sc = (((o >> 4) & 7) ^ (row & 7)) * 16;    // swizzled source k-bytes
      gl2lds16((const char*)A + ((size_t)(bm + row) * K + k0) * 2 + sc,
               (char*)As + (o - lane * 16));
      gl2lds16((const char*)Bt + ((size_t)(bn + row) * K + k0) * 2 + sc,
               (char*)Bs + (o - lane * 16));
    }
    __syncthreads();

#pragma unroll
    for (int kc = 0; kc < 2; ++kc) {
      bf16x8 aA[4], bB[4];
#pragma unroll
      for (int mt = 0; mt < 4; ++mt)
        aA[mt] = *(const bf16x8*)&As[(wm + mt * 16 + l16) * 64 +
                                     (((kc * 4 + quad) ^ r7) * 8)];
#pragma unroll
      for (int nt = 0; nt < 4; ++nt)
        bB[nt] = *(const bf16x8*)&Bs[(wn + nt * 16 + l16) * 64 +
                                     (((kc * 4 + quad) ^ r7) * 8)];
#pragma unroll
      for (int mt = 0; mt < 4; ++mt)
#pragma unroll
        for (int nt = 0; nt < 4; ++nt)
          acc[mt][nt] = __builtin_amdgcn_mfma_f32_16x16x32_bf16(
              aA[mt], bB[nt], acc[mt][nt], 0, 0, 0);
    }
  }

  const int row0 = bm + wm + quad * 4;
  const int col0 = bn + wn + l16;
  if (c_bf16) {
    const float sc = (bn < q_cols) ? q_scale : 1.0f;
    short* Cb = (short*)C;
#pragma unroll
    for (int mt = 0; mt < 4; ++mt)
#pragma unroll
      for (int nt = 0; nt < 4; ++nt)
#pragma unroll
        for (int r = 0; r < 4; ++r)
          Cb[(size_t)(row0 + mt * 16 + r) * N + col0 + nt * 16] =
              f2bf(acc[mt][nt][r] * sc);
  } else {
    float* Cf = (float*)C;
    float bv[4];
#pragma unroll
    for (int nt = 0; nt < 4; ++nt) bv[nt] = bias ? bias[col0 + nt * 16] : 0.f;
#pragma unroll
    for (int mt = 0; mt < 4; ++mt)
#pragma unroll
      for (int nt = 0; nt < 4; ++nt)
#pragma unroll
        for (int r = 0; r < 4; ++r)
          Cf[(size_t)(row0 + mt * 16 + r) * N + col0 + nt * 16] =
              acc[mt][nt][r] + bv[nt];
  }
}

// ---------------------------------------------------------------------------
// bf16-MFMA flash attention, swapped-QK^T 32x32, 8-wave / 256-Q-row blocks.
// FROZEN at the round-8/10 proven state (~92 us, VGPR 64, no spill):
// exp2 via builtin, WRITEV between jt=0/jt=1, tree rowsum, setprio.
// ---------------------------------------------------------------------------
#define LSTR 72  // Vt row stride in bf16 (144 B): skewed banks + b128 aligned

typedef union { unsigned u[4]; bf16x8 v; } U8;

__global__ __launch_bounds__(512, 4) void attn_flash_mfma32(
    const short* __restrict__ qkv, short* __restrict__ attn_out) {
  __shared__ short Kt[2][64 * 64];    // linear; content XOR-swizzled
  __shared__ short Vt[2][64 * LSTR];  // Vt[d][j] (transposed), skewed
  // XCD-chunked bijective swizzle: 8 consecutive logical blocks (the 8
  // q-blocks sharing one (b,h) K/V stream) land on ONE XCD's L2.
  const int wg = (blockIdx.x & 7) * 64 + (blockIdx.x >> 3);
  const int qb = wg & 7, h = (wg >> 3) & 15, b = wg >> 7;
  const int q0 = qb * 256;
  const int t    = threadIdx.x;
  const int w    = t >> 6;
  const int lane = t & 63;
  const int l32  = lane & 31;
  const int hi   = lane >> 5;

  const short* base = qkv + (size_t)b * SEQ * QKVC;

  // Q B-fragments (loop-invariant): col=q=l32, k=d = dc*16 + hi*8 + e
  bf16x8 bQ[4];
  {
    const short* qp = base + (size_t)(q0 + w * 32 + l32) * QKVC + h * DHEAD + hi * 8;
#pragma unroll
    for (int dc = 0; dc < 4; ++dc) bQ[dc] = *(const bf16x8*)(qp + dc * 16);
  }

  // K staging: 512 lanes x 16B = whole 64x64 tile in one gl2lds per thread.
  // Lane covers dest row kj = w*8 + (lane>>3), chunk c = lane&7; source
  // chunk = c ^ (kj&7)  (inverse XOR applied at source; read applies same).
  const int kj = w * 8 + (lane >> 3);
  const int kc = (lane & 7) ^ (kj & 7);
  const short* ksrc = base + (size_t)kj * QKVC + DMODEL + h * DHEAD + kc * 8;

  // V staging: thread t -> j-pair rows {2p,2p+1}, d cols q4..q4+3.
  const int pv = t & 31, q4 = (t >> 5) * 4;
  const short* vsrc = base + (size_t)(2 * pv) * QKVC + 2 * DMODEL + h * DHEAD + q4;
  ushort4 va, vb;  // V prefetch regs (rows 2p, 2p+1)

  auto LOADK = [&](int j0, int buf) {
    gl2lds16(ksrc + (size_t)j0 * QKVC, (char*)&Kt[buf][0] + w * 1024);
  };
  auto LOADV = [&](int j0) {
    const short* vp = vsrc + (size_t)j0 * QKVC;
    va = *(const ushort4*)vp;
    vb = *(const ushort4*)(vp + QKVC);
  };
  auto WRITEV = [&](int buf) {
    unsigned* vd = (unsigned*)&Vt[buf][q4 * LSTR + 2 * pv];
    vd[0]   = (unsigned)va.x | ((unsigned)vb.x << 16);
    vd[36]  = (unsigned)va.y | ((unsigned)vb.y << 16);  // +LSTR shorts = 36 dw
    vd[72]  = (unsigned)va.z | ((unsigned)vb.z << 16);
    vd[108] = (unsigned)va.w | ((unsigned)vb.w << 16);
  };

  f32x16 O0, O1;
#pragma unroll
  for (int i = 0; i < 16; ++i) { O0[i] = 0.f; O1[i] = 0.f; }
  float rs = 0.f;

  LOADK(0, 0);
  LOADV(0);
  WRITEV(0);
  __syncthreads();  // vmcnt(0)+lgkmcnt(0) drain: K in LDS, V written

  int cur = 0;
  for (int j0 = 0; j0 < SEQ; j0 += 64) {
    const bool nxt = (j0 + 64) < SEQ;
    if (nxt) {                      // issue next tile's loads; latency hides
      LOADK(j0 + 64, cur ^ 1);      // buf cur^1 fully consumed at last barrier
      LOADV(j0 + 64);
    }

    const short* KtC = Kt[cur];
    const short* VtC = Vt[cur];
    const int r7 = l32 & 7;
#pragma unroll
    for (int jt = 0; jt < 2; ++jt) {
      // S^T = K (rows j) x Q^T: A row = j = jt*32 + l32, k = d
      f32x16 accS;
#pragma unroll
      for (int i = 0; i < 16; ++i) accS[i] = 0.f;
      const short* ktb = KtC + (jt * 32 + l32) * 64;
      __builtin_amdgcn_s_setprio(1);
#pragma unroll
      for (int dc = 0; dc < 4; ++dc) {
        bf16x8 aK = *(const bf16x8*)(ktb + (((dc << 1) | hi) ^ r7) * 8);
        accS = __builtin_amdgcn_mfma_f32_32x32x16_bf16(aK, bQ[dc], accS, 0, 0, 0);
      }
      __builtin_amdgcn_s_setprio(0);
      // lane holds S[q=l32][j = jt*32 + (r&3)+8*(r>>2)+4*hi], r=0..15
      float p[16];
#pragma unroll
      for (int r = 0; r < 16; ++r) p[r] = exp2_hw(accS[r]);
      {  // tree rowsum: transient temps only, dep chain 16 -> 5
        float t0 = (p[0] + p[1]) + (p[2] + p[3]);
        float t1 = (p[4] + p[5]) + (p[6] + p[7]);
        float t2 = (p[8] + p[9]) + (p[10] + p[11]);
        float t3 = (p[12] + p[13]) + (p[14] + p[15]);
        rs += (t0 + t1) + (t2 + t3);
      }
      // pack pairs (j,j+1) then swap hi<->lo halves -> contiguous k=8 frags
      unsigned ua = cvtpk_bf16(p[0], p[1]),   ub = cvtpk_bf16(p[2], p[3]);
      unsigned uc = cvtpk_bf16(p[4], p[5]),   ud = cvtpk_bf16(p[6], p[7]);
      unsigned ue = cvtpk_bf16(p[8], p[9]),   uf = cvtpk_bf16(p[10], p[11]);
      unsigned ug = cvtpk_bf16(p[12], p[13]), uh = cvtpk_bf16(p[14], p[15]);
      plswap(ua, uc); plswap(ub, ud);  // frag jc=jt*2:   words {ua,ub,uc,ud}
      plswap(ue, ug); plswap(uf, uh);  // frag jc=jt*2+1: words {ue,uf,ug,uh}
      U8 fa, fb;
      fa.u[0] = ua; fa.u[1] = ub; fa.u[2] = uc; fa.u[3] = ud;
      fb.u[0] = ue; fb.u[1] = uf; fb.u[2] = ug; fb.u[3] = uh;
      // PV: O[q][d] += P[q][j] V[j][d]; B col = d = dt*32 + l32, k = j
      __builtin_amdgcn_s_setprio(1);
#pragma unroll
      for (int dt = 0; dt < 2; ++dt) {
        const short* vt = VtC + (dt * 32 + l32) * LSTR + hi * 8;
        bf16x8 bV0 = *(const bf16x8*)(vt + (jt * 2) * 16);
        bf16x8 bV1 = *(const bf16x8*)(vt + (jt * 2 + 1) * 16);
        f32x16& Od = dt ? O1 : O0;
        Od = __builtin_amdgcn_mfma_f32_32x32x16_bf16(fa.v, bV0, Od, 0, 0, 0);
        Od = __builtin_amdgcn_mfma_f32_32x32x16_bf16(fb.v, bV1, Od, 0, 0, 0);
      }
      __builtin_amdgcn_s_setprio(0);
      // After jt=0: write next tile's V (buf cur^1, disjoint from all reads
      // of cur this epoch). V global loads have had a half-tile of compute
      // to land; ds_writes overlap jt=1 instead of stalling pre-barrier.
      if (jt == 0 && nxt) WRITEV(cur ^ 1);
    }

    if (nxt) {
      __syncthreads();   // single barrier per KV tile (drains gl2lds too)
      cur ^= 1;
    }
  }

  // rs: lane l holds partial row-sum for q=l32 (hi halves cover disjoint j)
  rs += __shfl_xor(rs, 32, 64);
  const float inv_own = 1.f / rs;
  short* op0 = attn_out + ((size_t)b * SEQ + q0 + w * 32) * DMODEL + h * DHEAD + l32;
#pragma unroll
  for (int r = 0; r < 16; ++r) {
    const int q = (r & 3) + 8 * (r >> 2) + 4 * hi;  // O row for this reg
    const float inv = __shfl(inv_own, q, 64);       // lane q holds 1/rowsum(q)
    short* op = op0 + (size_t)q * DMODEL;
    op[0]  = f2bf(O0[r] * inv);
    op[32] = f2bf(O1[r] * inv);
  }
}

// ---------------------------------------------------------------------------
// Launch: fused convert -> bf16 GEMM (qkv, Q pre-scaled) -> attn -> GEMM+bias
// Workspace (bf16): xb 16MB | wqbt 6MB | wobt 2MB | qkvb 48MB | attnb 16MB
// ---------------------------------------------------------------------------
extern "C" void kernel_launch(void* const* d_in, const int* in_sizes, int n_in,
                              void* d_out, int out_size, void* d_ws, size_t ws_size,
                              hipStream_t stream) {
  const float* x     = (const float*)d_in[0];
  const float* w_qkv = (const float*)d_in[1];
  const float* w_out = (const float*)d_in[2];
  const float* b_out = (const float*)d_in[3];
  float* out = (float*)d_out;

  short* xb    = (short*)d_ws;                       // 8192*1024
  short* wqbt  = xb   + (size_t)8192 * 1024;         // 3072*1024 (w_qkv^T)
  short* wobt  = wqbt + (size_t)3072 * 1024;         // 1024*1024 (w_out^T)
  short* qkvb  = wobt + (size_t)1024 * 1024;         // 8192*3072
  short* attnb = qkvb + (size_t)8192 * 3072;         // 8192*1024

  fused_pre<<<dim3(4096 + 768 + 256), 256, 0, stream>>>(
      x, xb, w_qkv, wqbt, w_out, wobt);

  gemm_bf16_128<<<dim3((QKVC / 128) * ((NB * SEQ) / 128)), 256, 0, stream>>>(
      xb, wqbt, nullptr, qkvb, NB * SEQ, QKVC, DMODEL, 1, QSCALE_LOG2E, DMODEL);

  attn_flash_mfma32<<<dim3(512), 512, 0, stream>>>(qkvb, attnb);

  gemm_bf16_128<<<dim3((DMODEL / 128) * ((NB * SEQ) / 128)), 256, 0, stream>>>(
      attnb, wobt, b_out, out, NB * SEQ, DMODEL, DMODEL, 0, 1.0f, 0);
}